// Round 5
// baseline (409.874 us; speedup 1.0000x reference)
//
#include <hip/hip_runtime.h>

typedef __attribute__((ext_vector_type(8))) short     bf16x8;
typedef __attribute__((ext_vector_type(4))) float     f32x4;
typedef __attribute__((ext_vector_type(2))) float     f32x2;

#define OUT_STRIDE 1086
#define NS_STRIDE 1026
#define NS_BASE (4096*1086)

// LDS byte offsets inside mega
#define HA_OFF 0        // h_tm1 (later h)  : 16 x 1024 bf16, row stride 2048, swizzled
#define RH_OFF 32768    // r*h              : same
#define ZB_OFF 65536    // z gate bf16      : same
#define B_OFF  98304    // B ring: 6 units x 8192 B
// total 147456 B

__device__ __forceinline__ unsigned short f2bf(float x) {
  unsigned int u = __float_as_uint(x);
  unsigned int r = (u + 0x7FFFu + ((u >> 16) & 1u)) >> 16;
  return (unsigned short)r;
}
__device__ __forceinline__ float bf2f(unsigned short u) {
  union { unsigned int i; float f; } v; v.i = ((unsigned int)u) << 16; return v.f;
}
__device__ __forceinline__ float sigmoidf(float x) { return 1.f / (1.f + expf(-x)); }

__device__ __forceinline__ void gld_lds16(const void* g, void* l) {
  __builtin_amdgcn_global_load_lds((const __attribute__((address_space(1))) void*)g,
                                   (__attribute__((address_space(3))) void*)l, 16, 0, 0);
}

// XOR-swizzle within a 2048B row: balances the 8 16B bank-slots across rows.
__device__ __forceinline__ int swz(int row, int koff) {
  return row * 2048 + (koff ^ ((row & 7) << 4));
}

// ---------- transpose-convert R (1024 x 4096 f32) -> RbT (4096 x 1024 bf16) ----------
__global__ __launch_bounds__(256)
void transposeR(const float* __restrict__ R, unsigned short* __restrict__ Bt) {
  __shared__ float t[64][65];
  const int tx = threadIdx.x & 63, ty = threadIdx.x >> 6;
  const int j0 = blockIdx.x * 64, k0 = blockIdx.y * 64;
#pragma unroll
  for (int i = 0; i < 64; i += 4)
    t[ty + i][tx] = R[(size_t)(k0 + ty + i) * 4096 + j0 + tx];
  __syncthreads();
#pragma unroll
  for (int i = 0; i < 64; i += 4) {
    const int j = ty + i;
    Bt[(size_t)(j0 + j) * 1024 + k0 + tx] = f2bf(t[tx][j]);
  }
}

// ---------- megafused: all three GEMMs + gate epilogues, 16 rows per block ----------
__global__ __launch_bounds__(512, 2)
void mega(const unsigned short* __restrict__ Bt,   // RbT [4096][1024] bf16
          const int* __restrict__ chv,
          const float* __restrict__ states,
          const float* __restrict__ kcm,
          const float* __restrict__ kd,
          const float* __restrict__ bias_z,
          const float* __restrict__ bias,
          float* __restrict__ out,
          float* __restrict__ ns) {
  __shared__ __align__(16) char lds[147456];
  const int tid = threadIdx.x, lane = tid & 63, wave = tid >> 6;
  const int fr = lane & 15, fq = lane >> 4;          // frag col / k-quarter (C: col=fr, row=fq*4+i)
  const int r0 = blockIdx.x * 16;

  // per-thread epilogue row constants (rows fq*4+i are fixed per thread)
  int chr_[4]; float d0r[4], d1r[4];
#pragma unroll
  for (int i = 0; i < 4; ++i) {
    const int grow = r0 + fq * 4 + i;
    chr_[i] = chv[grow];
    d0r[i] = states[(size_t)grow * 1026 + 1024];
    d1r[i] = states[(size_t)grow * 1026 + 1025];
  }

  // staging geometry: thread t loads 16B = col (t>>2), k-elems [(t&3)*8, +8) of a 128x32 chunk
  const size_t soff = (size_t)(tid >> 2) * 1024 + (size_t)(tid & 3) * 8;

  auto stage1 = [&](int g) {  // GEMM1: z-panel + r-panel units, ring-6
    const int tile = g >> 5, k0 = (g & 31) * 32;
    const size_t src = (size_t)(tile * 128) * 1024 + k0 + soff;
    gld_lds16(Bt + src,                       lds + B_OFF + ((2 * g)     % 6) * 8192 + tid * 16);
    gld_lds16(Bt + (size_t)1024 * 1024 + src, lds + B_OFF + ((2 * g + 1) % 6) * 8192 + tid * 16);
  };
  stage1(0); stage1(1);

  // load h_tm1 rows -> hA (bf16, swizzled). thread t: row t>>5, cols (t&31)*32 .. +32
  {
    const int tr = tid >> 5, cb = (tid & 31) * 32;
    const float* sp = states + (size_t)(r0 + tr) * 1026 + cb;
#pragma unroll
    for (int j = 0; j < 4; ++j) {
      f32x4 a = *(const f32x4*)(sp + j * 8);
      f32x4 b = *(const f32x4*)(sp + j * 8 + 4);
      union { unsigned short us[8]; bf16x8 v; } u;
      u.us[0] = f2bf(a[0]); u.us[1] = f2bf(a[1]); u.us[2] = f2bf(a[2]); u.us[3] = f2bf(a[3]);
      u.us[4] = f2bf(b[0]); u.us[5] = f2bf(b[1]); u.us[6] = f2bf(b[2]); u.us[7] = f2bf(b[3]);
      *(bf16x8*)(lds + HA_OFF + swz(tr, cb * 2 + j * 16)) = u.v;
    }
  }
  __syncthreads();

  const int bro = (wave * 16 + fr) * 64 + fq * 16;   // B-frag byte offset within a unit
  const f32x4 zero4 = {0.f, 0.f, 0.f, 0.f};

  // ================= GEMM1: z,r (B cols 0..2047), A = hA =================
  {
    f32x4 accz = zero4, accr = zero4;
    for (int g = 0; g < 256; ++g) {
      const int k0 = (g & 31) * 32;
      if (g < 255) asm volatile("s_waitcnt vmcnt(2)" ::: "memory");
      else         asm volatile("s_waitcnt vmcnt(0)" ::: "memory");
      __builtin_amdgcn_s_barrier();
      bf16x8 af  = *(const bf16x8*)(lds + HA_OFF + swz(fr, k0 * 2 + fq * 16));
      bf16x8 bzf = *(const bf16x8*)(lds + B_OFF + ((2 * g)     % 6) * 8192 + bro);
      bf16x8 brf = *(const bf16x8*)(lds + B_OFF + ((2 * g + 1) % 6) * 8192 + bro);
      if (g + 2 < 256) stage1(g + 2);
      accz = __builtin_amdgcn_mfma_f32_16x16x32_bf16(af, bzf, accz, 0, 0, 0);
      accr = __builtin_amdgcn_mfma_f32_16x16x32_bf16(af, brf, accr, 0, 0, 0);
      if ((g & 31) == 31) {
        const int c = (g >> 5) * 128 + wave * 16 + fr;
#pragma unroll
        for (int i = 0; i < 4; ++i) {
          const int row = fq * 4 + i, grow = r0 + row;
          const float* kcr = kcm + (size_t)chr_[i] * 4096;
          const float vz = accz[i] + kcr[c]        + d0r[i] * kd[c]        + d1r[i] * kd[4096 + c]        + bias_z[c];
          const float vr = accr[i] + kcr[1024 + c] + d0r[i] * kd[1024 + c] + d1r[i] * kd[4096 + 1024 + c] + bias[c];
          const float z  = sigmoidf(vz);
          const float rr = sigmoidf(vr);
          const float htm = states[(size_t)grow * 1026 + c];
          *(unsigned short*)(lds + ZB_OFF + swz(row, c * 2)) = f2bf(z);
          *(unsigned short*)(lds + RH_OFF + swz(row, c * 2)) = f2bf(rr * htm);
        }
        accz = zero4; accr = zero4;
      }
    }
  }
  __syncthreads();

  // ================= GEMM2: hh -> h (B cols 2048..3071), A = rh =================
  auto stageN = [&](int g, const unsigned short* Bp) {  // single panel, ring-3
    const int tile = g >> 5, k0 = (g & 31) * 32;
    gld_lds16(Bp + (size_t)(tile * 128) * 1024 + k0 + soff,
              lds + B_OFF + (g % 3) * 8192 + tid * 16);
  };
  {
    const unsigned short* Bp = Bt + (size_t)2048 * 1024;
    stageN(0, Bp); stageN(1, Bp);
    f32x4 acc = zero4;
    for (int g = 0; g < 256; ++g) {
      const int k0 = (g & 31) * 32;
      if (g < 255) asm volatile("s_waitcnt vmcnt(1)" ::: "memory");
      else         asm volatile("s_waitcnt vmcnt(0)" ::: "memory");
      __builtin_amdgcn_s_barrier();
      bf16x8 af = *(const bf16x8*)(lds + RH_OFF + swz(fr, k0 * 2 + fq * 16));
      bf16x8 bf_ = *(const bf16x8*)(lds + B_OFF + (g % 3) * 8192 + bro);
      if (g + 2 < 256) stageN(g + 2, Bp);
      acc = __builtin_amdgcn_mfma_f32_16x16x32_bf16(af, bf_, acc, 0, 0, 0);
      if ((g & 31) == 31) {
        const int c = (g >> 5) * 128 + wave * 16 + fr;
#pragma unroll
        for (int i = 0; i < 4; ++i) {
          const int row = fq * 4 + i, grow = r0 + row;
          const float* kcr = kcm + (size_t)chr_[i] * 4096;
          const float v = acc[i] + kcr[2048 + c] + d0r[i] * kd[2048 + c] + d1r[i] * kd[4096 + 2048 + c] + bias[1024 + c];
          const float hh = tanhf(v);
          const float z  = bf2f(*(const unsigned short*)(lds + ZB_OFF + swz(row, c * 2)));
          const float htm = states[(size_t)grow * 1026 + c];
          const float h = z * htm + (1.f - z) * hh;
          ns[(size_t)grow * NS_STRIDE + c] = h;
          *(unsigned short*)(lds + HA_OFF + swz(row, c * 2)) = f2bf(h);
        }
        acc = zero4;
      }
    }
  }
  __syncthreads();

  // ================= GEMM3: o (B cols 3072..4095), A = hA (now h) =================
  {
    const unsigned short* Bp = Bt + (size_t)3072 * 1024;
    stageN(0, Bp); stageN(1, Bp);
    f32x4 acc = zero4;
    for (int g = 0; g < 256; ++g) {
      const int k0 = (g & 31) * 32;
      if (g < 255) asm volatile("s_waitcnt vmcnt(1)" ::: "memory");
      else         asm volatile("s_waitcnt vmcnt(0)" ::: "memory");
      __builtin_amdgcn_s_barrier();
      bf16x8 af = *(const bf16x8*)(lds + HA_OFF + swz(fr, k0 * 2 + fq * 16));
      bf16x8 bf_ = *(const bf16x8*)(lds + B_OFF + (g % 3) * 8192 + bro);
      if (g + 2 < 256) stageN(g + 2, Bp);
      acc = __builtin_amdgcn_mfma_f32_16x16x32_bf16(af, bf_, acc, 0, 0, 0);
      if ((g & 31) == 31) {
        const int c = (g >> 5) * 128 + wave * 16 + fr;
#pragma unroll
        for (int i = 0; i < 4; ++i) {
          const int row = fq * 4 + i, grow = r0 + row;
          const float* kcr = kcm + (size_t)chr_[i] * 4096;
          const float v = acc[i] + kcr[3072 + c] + d0r[i] * kd[3072 + c] + d1r[i] * kd[4096 + 3072 + c] + bias[2048 + c];
          out[(size_t)grow * OUT_STRIDE + c] = tanhf(v);
        }
        acc = zero4;
      }
    }
  }
}

// ---------- GMM head: gmm = o @ Wg + bg ; softmax ; preds ----------
__global__ __launch_bounds__(512)
void gmm_kernel(const float* __restrict__ obuf,
                const float* __restrict__ Wg,
                const float* __restrict__ bg,
                float* __restrict__ outp,
                float* __restrict__ ns) {
  __shared__ float Wl[128 * 60 + 16];
  __shared__ float ol[8 * 1024];
  const int tid = threadIdx.x;
  const int lane = tid & 63;
  const int wave = tid >> 6;
  const int row0 = blockIdx.x * 8;

  for (int i = tid; i < 4096; i += 512) {
    const int rr = i >> 9, c2 = (i & 511) * 2;
    *(f32x2*)&ol[rr * 1024 + c2] = *(const f32x2*)&obuf[(size_t)(row0 + rr) * OUT_STRIDE + c2];
  }

  float g = 0.f;
  for (int kc0 = 0; kc0 < 1024; kc0 += 128) {
    __syncthreads();
    for (int i = tid; i < 1920; i += 512)
      *(f32x4*)&Wl[i * 4] = *(const f32x4*)&Wg[kc0 * 60 + i * 4];
    __syncthreads();
    const float* orow = &ol[wave * 1024 + kc0];
#pragma unroll 8
    for (int k = 0; k < 128; ++k)
      g = fmaf(orow[k], Wl[k * 60 + lane], g);
  }
  if (lane < 60) g += bg[lane];

  float e = 0.f;
  if (lane < 20) e = fminf(fmaxf(expf(g), 1e-10f), 1e10f);
  float s = e;
#pragma unroll
  for (int m = 1; m < 32; m <<= 1) s += __shfl_xor(s, m, 64);
  const float pi = (lane < 20) ? e / s : 0.f;
  const int src1 = (lane < 20) ? lane + 20 : lane;
  const int src2 = (lane < 20) ? lane + 40 : lane;
  const float mux = __shfl(g, src1, 64);
  const float muy = __shfl(g, src2, 64);
  float px = pi * mux, py = pi * muy;
#pragma unroll
  for (int m = 1; m < 32; m <<= 1) { px += __shfl_xor(px, m, 64); py += __shfl_xor(py, m, 64); }

  const int row = row0 + wave;
  float* orow = outp + (size_t)row * OUT_STRIDE;
  if (lane < 20) orow[1024 + lane] = pi;
  else if (lane < 60) orow[1024 + lane] = g;
  if (lane == 0) {
    orow[1084] = px;
    orow[1085] = py;
    ns[(size_t)row * NS_STRIDE + 1024] = px;
    ns[(size_t)row * NS_STRIDE + 1025] = py;
  }
}

extern "C" void kernel_launch(void* const* d_in, const int* in_sizes, int n_in,
                              void* d_out, int out_size, void* d_ws, size_t ws_size,
                              hipStream_t stream) {
  const int*   chv    = (const int*)d_in[0];
  const float* states = (const float*)d_in[1];
  const float* bias_z = (const float*)d_in[2];
  const float* R      = (const float*)d_in[3];
  const float* kc     = (const float*)d_in[4];
  const float* bias   = (const float*)d_in[5];
  const float* kd     = (const float*)d_in[6];
  const float* Wg     = (const float*)d_in[7];
  const float* bg     = (const float*)d_in[8];
  float* out = (float*)d_out;

  unsigned short* RbT = (unsigned short*)d_ws;   // 8 MB

  transposeR<<<dim3(64, 16), 256, 0, stream>>>(R, RbT);

  mega<<<256, 512, 0, stream>>>(RbT, chv, states, kc, kd, bias_z, bias,
                                out, out + NS_BASE);

  gmm_kernel<<<512, 512, 0, stream>>>(out, Wg, bg, out, out + NS_BASE);
}

// Round 8
// 356.963 us; speedup vs baseline: 1.1482x; 1.1482x over previous
//
#include <hip/hip_runtime.h>

typedef __attribute__((ext_vector_type(8))) short     bf16x8;
typedef __attribute__((ext_vector_type(4))) float     f32x4;
typedef __attribute__((ext_vector_type(2))) float     f32x2;
typedef __attribute__((ext_vector_type(4))) unsigned short u16x4;

#define OUT_STRIDE 1086
#define NS_STRIDE 1026
#define NS_BASE (4096*1086)

__device__ __forceinline__ unsigned short f2bf(float x) {
  unsigned int u = __float_as_uint(x);
  unsigned int r = (u + 0x7FFFu + ((u >> 16) & 1u)) >> 16;
  return (unsigned short)r;
}
__device__ __forceinline__ float bf2f(unsigned short u) {
  union { unsigned int i; float f; } v; v.i = ((unsigned int)u) << 16; return v.f;
}
__device__ __forceinline__ float sigmoidf(float x) { return 1.f / (1.f + expf(-x)); }

__device__ __forceinline__ void gld_lds16(const void* g, void* l) {
  __builtin_amdgcn_global_load_lds((const __attribute__((address_space(1))) void*)g,
                                   (__attribute__((address_space(3))) void*)l, 16, 0, 0);
}

// ---------- transpose-convert R (1024 x 4096 f32) -> RbT (4096 x 1024 bf16) ----------
__global__ __launch_bounds__(256)
void transposeR(const float* __restrict__ R, unsigned short* __restrict__ Bt) {
  __shared__ float t[64][65];
  const int tx = threadIdx.x & 63, ty = threadIdx.x >> 6;
  const int j0 = blockIdx.x * 64, k0 = blockIdx.y * 64;
#pragma unroll
  for (int i = 0; i < 64; i += 4)
    t[ty + i][tx] = R[(size_t)(k0 + ty + i) * 4096 + j0 + tx];
  __syncthreads();
#pragma unroll
  for (int i = 0; i < 64; i += 4) {
    const int j = ty + i;
    Bt[(size_t)(j0 + j) * 1024 + k0 + tx] = f2bf(t[tx][j]);
  }
}

// ---------- convert h_tm1 -> bf16 ----------
__global__ __launch_bounds__(256)
void convertH(const float* __restrict__ states, unsigned short* __restrict__ hb) {
  const int idx = blockIdx.x * 256 + threadIdx.x;
  const int b = idx >> 8, u = (idx & 255) * 4;
  const float* sp = states + (size_t)b * 1026 + u;
  f32x2 v0 = *(const f32x2*)sp, v1 = *(const f32x2*)(sp + 2);
  u16x4 w;
  w[0] = f2bf(v0[0]); w[1] = f2bf(v0[1]); w[2] = f2bf(v1[0]); w[3] = f2bf(v1[1]);
  *(u16x4*)&hb[(size_t)b * 1024 + u] = w;
}

// ================= fat-wave GEMM template =================
// C[4096, 128*NTN] = A[4096,1024] @ Bt[colbase + n, :]^T
// tile 128x128, 4 waves (2M x 2N), per-wave 64x64 (16 frags), K-step 32,
// ring-4 LDS, counted vmcnt depth-2, slot^row&3 swizzle (both sides).
// EPI 1: z/r gate epilogue (split on n0).  EPI 2: hh->h.  EPI 3: o.
template<int EPI, int NTN>
__global__ __launch_bounds__(256, 2)
void gemm_bt(const unsigned short* __restrict__ A,
             const unsigned short* __restrict__ Bt, int colbase,
             const int* __restrict__ chv,
             const float* __restrict__ states,
             const float* __restrict__ kcm,
             const float* __restrict__ kd,
             const float* __restrict__ bias_z,
             const float* __restrict__ bias,
             float* __restrict__ zbuf,
             unsigned short* __restrict__ rh,
             float* __restrict__ outp,
             unsigned short* __restrict__ hb2) {
  __shared__ __align__(16) char ldsb[65536];   // A ring: 4 x 8KB @0, B ring: 4 x 8KB @32768
  __shared__ int   chs[128];
  __shared__ float d0s[128], d1s[128];

  const int tid = threadIdx.x, lane = tid & 63, wave = tid >> 6;
  const int wr = wave >> 1, wc = wave & 1;
  const int arow = lane & 15, q = lane >> 4;
  const int bid = blockIdx.x;

  int mt, nt;
  if (NTN == 16) {               // 512 blocks: 8 XCD chunks of 8m x 8n
    const int swz = (bid & 7) * 64 + (bid >> 3);
    const int chunk = swz >> 6, l = swz & 63;
    mt = (chunk & 3) * 8 + (l >> 3);
    nt = (chunk >> 2) * 8 + (l & 7);
  } else {                       // 256 blocks: XCD x gets 4m x 8n
    const int xcd = bid & 7, j = bid >> 3;
    mt = xcd * 4 + (j >> 3);
    nt = j & 7;
  }
  const int m0 = mt * 128, n0 = nt * 128;

  if (tid < 128) {
    const int r = m0 + tid;
    chs[tid] = chv[r];
    d0s[tid] = states[(size_t)r * 1026 + 1024];
    d1s[tid] = states[(size_t)r * 1026 + 1025];
  }

  const unsigned short* Ag = A  + (size_t)m0 * 1024;
  const unsigned short* Bg = Bt + (size_t)(colbase + n0) * 1024;

  f32x4 acc[4][4] = {};

  // stage: chunk c in [0,512): row=c>>2, lds-slot=c&3 holds global k-slot (c&3)^(row&3).
  // LDS dest linear (c*16) => wave-uniform base + lane*16. Global source pre-swizzled.
#define ST1(c, G, Loff, kk) {                                                  \
    const int row_ = (c) >> 2;                                                 \
    const int ss_  = ((c) & 3) ^ (row_ & 3);                                   \
    gld_lds16(G + (size_t)row_ * 1024 + (kk) + ss_ * 8, ldsb + (Loff) + (c) * 16); }
#define STAGE(b, kk) {                                                         \
    ST1(tid,       Ag, (b) * 8192,         kk)                                 \
    ST1(tid + 256, Ag, (b) * 8192,         kk)                                 \
    ST1(tid,       Bg, 32768 + (b) * 8192, kk)                                 \
    ST1(tid + 256, Bg, 32768 + (b) * 8192, kk) }

  const int sq = (q ^ (arow & 3)) << 4;   // swizzled 16B-slot byte offset for reads

  auto compute = [&](int cb) {
    bf16x8 af[4], bfr[4];
    const char* Ab = ldsb + cb * 8192;
    const char* Bb = ldsb + 32768 + cb * 8192;
#pragma unroll
    for (int mi = 0; mi < 4; ++mi) {
      const int R = wr * 64 + mi * 16 + arow;
      af[mi] = *(const bf16x8*)(Ab + R * 64 + sq);
    }
#pragma unroll
    for (int ni = 0; ni < 4; ++ni) {
      const int R = wc * 64 + ni * 16 + arow;
      bfr[ni] = *(const bf16x8*)(Bb + R * 64 + sq);
    }
    __builtin_amdgcn_s_setprio(1);
#pragma unroll
    for (int mi = 0; mi < 4; ++mi)
#pragma unroll
      for (int ni = 0; ni < 4; ++ni)
        acc[mi][ni] = __builtin_amdgcn_mfma_f32_16x16x32_bf16(af[mi], bfr[ni], acc[mi][ni], 0, 0, 0);
    __builtin_amdgcn_s_setprio(0);
  };

  STAGE(0, 0)
  STAGE(1, 32)
  for (int t = 0; t < 30; ++t) {
    STAGE((t + 2) & 3, (t + 2) * 32)
    asm volatile("s_waitcnt vmcnt(8)" ::: "memory");   // keep stages t+1,t+2 (8 loads) in flight
    __builtin_amdgcn_s_barrier();
    asm volatile("" ::: "memory");
    compute(t & 3);
  }
  asm volatile("s_waitcnt vmcnt(4)" ::: "memory");
  __builtin_amdgcn_s_barrier();
  asm volatile("" ::: "memory");
  compute(2);
  asm volatile("s_waitcnt vmcnt(0)" ::: "memory");
  __builtin_amdgcn_s_barrier();
  asm volatile("" ::: "memory");
  compute(3);
#undef STAGE
#undef ST1

  // ---------------- epilogue ----------------
#pragma unroll
  for (int mi = 0; mi < 4; ++mi) {
#pragma unroll
    for (int i = 0; i < 4; ++i) {
      const int lrow = wr * 64 + mi * 16 + q * 4 + i;
      const int grow = m0 + lrow;
      const int ch = chs[lrow];
      const float d0 = d0s[lrow], d1 = d1s[lrow];
      const float* kcr = kcm + (size_t)ch * 4096;
#pragma unroll
      for (int ni = 0; ni < 4; ++ni) {
        const int gc = n0 + wc * 64 + ni * 16 + arow;           // col within this GEMM's N
        const float a = acc[mi][ni][i];
        if (EPI == 1) {
          const int fullc = gc;
          const float pre = kcr[fullc] + d0 * kd[fullc] + d1 * kd[4096 + fullc];
          if (n0 < 1024) {
            const float z = sigmoidf(a + pre + bias_z[gc]);
            zbuf[(size_t)grow * 1024 + gc] = z;
          } else {
            const int uc = gc - 1024;
            const float r = sigmoidf(a + pre + bias[uc]);
            rh[(size_t)grow * 1024 + uc] = f2bf(r * states[(size_t)grow * 1026 + uc]);
          }
        } else if (EPI == 2) {
          const int fullc = 2048 + gc;
          const float v = a + kcr[fullc] + d0 * kd[fullc] + d1 * kd[4096 + fullc] + bias[1024 + gc];
          const float hh = tanhf(v);
          const float z = zbuf[(size_t)grow * 1024 + gc];
          const float htm = states[(size_t)grow * 1026 + gc];
          const float h = z * htm + (1.f - z) * hh;
          outp[(size_t)grow * NS_STRIDE + gc] = h;
          hb2[(size_t)grow * 1024 + gc] = f2bf(h);
        } else {
          const int fullc = 3072 + gc;
          const float v = a + kcr[fullc] + d0 * kd[fullc] + d1 * kd[4096 + fullc] + bias[2048 + gc];
          outp[(size_t)grow * OUT_STRIDE + gc] = tanhf(v);
        }
      }
    }
  }
}

// ---------- GMM head ----------
__global__ __launch_bounds__(512)
void gmm_kernel(const float* __restrict__ obuf,
                const float* __restrict__ Wg,
                const float* __restrict__ bg,
                float* __restrict__ outp,
                float* __restrict__ ns) {
  __shared__ float Wl[128 * 60 + 16];
  __shared__ float ol[8 * 1024];
  const int tid = threadIdx.x;
  const int lane = tid & 63;
  const int wave = tid >> 6;
  const int row0 = blockIdx.x * 8;

  for (int i = tid; i < 4096; i += 512) {
    const int rr = i >> 9, c2 = (i & 511) * 2;
    *(f32x2*)&ol[rr * 1024 + c2] = *(const f32x2*)&obuf[(size_t)(row0 + rr) * OUT_STRIDE + c2];
  }

  float g = 0.f;
  for (int kc0 = 0; kc0 < 1024; kc0 += 128) {
    __syncthreads();
    for (int i = tid; i < 1920; i += 512)
      *(f32x4*)&Wl[i * 4] = *(const f32x4*)&Wg[kc0 * 60 + i * 4];
    __syncthreads();
    const float* orow = &ol[wave * 1024 + kc0];
#pragma unroll 8
    for (int k = 0; k < 128; ++k)
      g = fmaf(orow[k], Wl[k * 60 + lane], g);
  }
  if (lane < 60) g += bg[lane];

  float e = 0.f;
  if (lane < 20) e = fminf(fmaxf(expf(g), 1e-10f), 1e10f);
  float s = e;
#pragma unroll
  for (int m = 1; m < 32; m <<= 1) s += __shfl_xor(s, m, 64);
  const float pi = (lane < 20) ? e / s : 0.f;
  const int src1 = (lane < 20) ? lane + 20 : lane;
  const int src2 = (lane < 20) ? lane + 40 : lane;
  const float mux = __shfl(g, src1, 64);
  const float muy = __shfl(g, src2, 64);
  float px = pi * mux, py = pi * muy;
#pragma unroll
  for (int m = 1; m < 32; m <<= 1) { px += __shfl_xor(px, m, 64); py += __shfl_xor(py, m, 64); }

  const int row = row0 + wave;
  float* orow = outp + (size_t)row * OUT_STRIDE;
  if (lane < 20) orow[1024 + lane] = pi;
  else if (lane < 60) orow[1024 + lane] = g;
  if (lane == 0) {
    orow[1084] = px;
    orow[1085] = py;
    ns[(size_t)row * NS_STRIDE + 1024] = px;
    ns[(size_t)row * NS_STRIDE + 1025] = py;
  }
}

extern "C" void kernel_launch(void* const* d_in, const int* in_sizes, int n_in,
                              void* d_out, int out_size, void* d_ws, size_t ws_size,
                              hipStream_t stream) {
  const int*   chv    = (const int*)d_in[0];
  const float* states = (const float*)d_in[1];
  const float* bias_z = (const float*)d_in[2];
  const float* R      = (const float*)d_in[3];
  const float* kc     = (const float*)d_in[4];
  const float* bias   = (const float*)d_in[5];
  const float* kd     = (const float*)d_in[6];
  const float* Wg     = (const float*)d_in[7];
  const float* bg     = (const float*)d_in[8];
  float* out = (float*)d_out;

  char* ws = (char*)d_ws;
  unsigned short* RbT  = (unsigned short*)ws;                   // 8 MB
  unsigned short* hb   = (unsigned short*)(ws + 8388608);       // 8 MB
  unsigned short* rh   = (unsigned short*)(ws + 16777216);      // 8 MB
  unsigned short* hb2  = (unsigned short*)(ws + 25165824);      // 8 MB
  float*          zbuf = (float*)(ws + 33554432);               // 16 MB

  transposeR<<<dim3(64, 16), 256, 0, stream>>>(R, RbT);
  convertH<<<4096, 256, 0, stream>>>(states, hb);

  // GEMM1: N=2048 (z cols 0..1023, r cols 1024..2047), fused gate epilogue
  gemm_bt<1, 16><<<512, 256, 0, stream>>>(hb, RbT, 0,
      chv, states, kc, kd, bias_z, bias, zbuf, rh, nullptr, nullptr);

  // GEMM2: hh -> h (new_state + h bf16)
  gemm_bt<2, 8><<<256, 256, 0, stream>>>(rh, RbT, 2048,
      chv, states, kc, kd, bias_z, bias, zbuf, nullptr, out + NS_BASE, hb2);

  // GEMM3: o -> out
  gemm_bt<3, 8><<<256, 256, 0, stream>>>(hb2, RbT, 3072,
      chv, states, kc, kd, bias_z, bias, nullptr, nullptr, out, nullptr);

  gmm_kernel<<<512, 512, 0, stream>>>(out, Wg, bg, out, out + NS_BASE);
}